// Round 1
// baseline (2291.297 us; speedup 1.0000x reference)
//
#include <hip/hip_runtime.h>
#include <hip/hip_bf16.h>
#include <math.h>

using bf16 = __hip_bfloat16;
typedef __bf16 bfv8 __attribute__((ext_vector_type(8)));
typedef float f32x4 __attribute__((ext_vector_type(4)));

__device__ __forceinline__ f32x4 mfma16(bfv8 a, bfv8 b, f32x4 c) {
    return __builtin_amdgcn_mfma_f32_16x16x32_bf16(a, b, c, 0, 0, 0);
}

__device__ __forceinline__ void gload_lds16(const void* g, void* l) {
    __builtin_amdgcn_global_load_lds(
        (const __attribute__((address_space(1))) void*)g,
        (__attribute__((address_space(3))) void*)l, 16, 0, 0);
}

// ---------------------------------------------------------------- cvt f32->bf16
__global__ void cvt_kernel(const float* __restrict__ in, bf16* __restrict__ out, long n8) {
    long u = (long)blockIdx.x * 256 + threadIdx.x;
    if (u >= n8) return;
    const float4* p = (const float4*)in + u * 2;
    float4 a = p[0], b = p[1];
    bf16 t8[8] = { __float2bfloat16(a.x), __float2bfloat16(a.y), __float2bfloat16(a.z), __float2bfloat16(a.w),
                   __float2bfloat16(b.x), __float2bfloat16(b.y), __float2bfloat16(b.z), __float2bfloat16(b.w) };
    *(int4*)(out + u * 8) = *(const int4*)t8;
}

// ---------------------------------------------------------------- layernorm (D=4096), fp32 in -> bf16 out
__global__ void layernorm_kernel(const float* __restrict__ x, const float* __restrict__ gw,
                                 const float* __restrict__ gb, bf16* __restrict__ out)
{
    const int D = 4096;
    int row = blockIdx.x, t = threadIdx.x;
    const float4* xr = (const float4*)(x + (size_t)row * D);
    float4 v[4];
    float s1 = 0.f, s2 = 0.f;
#pragma unroll
    for (int j = 0; j < 4; ++j) {
        v[j] = xr[t + j * 256];
        s1 += v[j].x + v[j].y + v[j].z + v[j].w;
        s2 += v[j].x * v[j].x + v[j].y * v[j].y + v[j].z * v[j].z + v[j].w * v[j].w;
    }
#pragma unroll
    for (int d = 1; d < 64; d <<= 1) { s1 += __shfl_xor(s1, d); s2 += __shfl_xor(s2, d); }
    __shared__ float red[8];
    int wave = t >> 6, lane = t & 63;
    if (lane == 0) { red[wave] = s1; red[4 + wave] = s2; }
    __syncthreads();
    s1 = red[0] + red[1] + red[2] + red[3];
    s2 = red[4] + red[5] + red[6] + red[7];
    float mu = s1 * (1.f / 4096.f);
    float var = s2 * (1.f / 4096.f) - mu * mu;
    float rs = rsqrtf(var + 1e-5f);
    bf16* orow = out + (size_t)row * D;
#pragma unroll
    for (int j = 0; j < 4; ++j) {
        int base = (t + j * 256) * 4;
        float xs[4] = { v[j].x, v[j].y, v[j].z, v[j].w };
        bf16 o4[4];
#pragma unroll
        for (int c = 0; c < 4; ++c)
            o4[c] = __float2bfloat16((xs[c] - mu) * rs * gw[base + c] + gb[base + c]);
        *(int2*)(orow + base) = *(const int2*)o4;
    }
}

// ---------------------------------------------------------------- RoPE in-place on bf16 [rows, nheads*128]
__global__ void rope_kernel(bf16* __restrict__ x, int nheads, int seqlen, long total) {
    long idx = (long)blockIdx.x * 256 + threadIdx.x;
    if (idx >= total) return;
    int j = (int)(idx & 63);
    long t2 = idx >> 6;
    int h = (int)(t2 % nheads);
    long row = t2 / nheads;
    int pos = (int)(row % seqlen);
    float inv = exp2f(-(float)j * 0.20762050593046015f);  // log2(10000)/64
    float ang = (float)pos * inv;
    float s, c;
    sincosf(ang, &s, &c);
    bf16* p = x + row * ((long)nheads * 128) + (long)h * 128 + j;
    float x0 = __bfloat162float(p[0]);
    float x1 = __bfloat162float(p[64]);
    p[0]  = __float2bfloat16(x0 * c - x1 * s);
    p[64] = __float2bfloat16(x1 * c + x0 * s);
}

// ---------------------------------------------------------------- GEMM: C[M,N] = A[M,K] x W[N,K]^T  (bf16, fp32 acc)
// MODE 0: store bf16; 1: silu->bf16; 2: mul by aux(bf16)->bf16; 3: +aux(f32) -> f32
template<int MODE>
__global__ void gemm_bt(const bf16* __restrict__ A, const bf16* __restrict__ W,
                        void* __restrict__ Cout, const void* __restrict__ aux,
                        int M, int N, int K)
{
    __shared__ bf16 Asm[128 * 32];
    __shared__ bf16 Bsm[128 * 32];
    const int t = threadIdx.x;
    const int wave = t >> 6, lane = t & 63;
    const int lr = lane & 15, lg = lane >> 4;
    const int wr = wave >> 1, wc = wave & 1;
    const int bm = blockIdx.y * 128, bn = blockIdx.x * 128;

    const f32x4 zero4 = { 0.f, 0.f, 0.f, 0.f };
    f32x4 acc[4][4];
#pragma unroll
    for (int m = 0; m < 4; ++m)
#pragma unroll
        for (int n = 0; n < 4; ++n) acc[m][n] = zero4;

    for (int k0 = 0; k0 < K; k0 += 32) {
#pragma unroll
        for (int p = 0; p < 2; ++p) {
            int u = p * 256 + t;
            int row = u >> 2, ch = u & 3;
            gload_lds16(A + (size_t)(bm + row) * K + k0 + ch * 8, &Asm[u * 8]);
            gload_lds16(W + (size_t)(bn + row) * K + k0 + ch * 8, &Bsm[u * 8]);
        }
        __syncthreads();
        bfv8 af[4], bfm[4];
#pragma unroll
        for (int m = 0; m < 4; ++m) af[m] = *(const bfv8*)&Asm[(wr * 64 + m * 16 + lr) * 32 + lg * 8];
#pragma unroll
        for (int n = 0; n < 4; ++n) bfm[n] = *(const bfv8*)&Bsm[(wc * 64 + n * 16 + lr) * 32 + lg * 8];
#pragma unroll
        for (int m = 0; m < 4; ++m)
#pragma unroll
            for (int n = 0; n < 4; ++n)
                acc[m][n] = mfma16(af[m], bfm[n], acc[m][n]);
        __syncthreads();
    }

    const int r0 = bm + wr * 64, c0 = bn + wc * 64;
#pragma unroll
    for (int m = 0; m < 4; ++m) {
#pragma unroll
        for (int n = 0; n < 4; ++n) {
#pragma unroll
            for (int i = 0; i < 4; ++i) {
                int r = r0 + m * 16 + lg * 4 + i;
                int c = c0 + n * 16 + lr;
                size_t idx = (size_t)r * N + c;
                float a = acc[m][n][i];
                if constexpr (MODE == 0) {
                    ((bf16*)Cout)[idx] = __float2bfloat16(a);
                } else if constexpr (MODE == 1) {
                    a = a / (1.f + expf(-a));
                    ((bf16*)Cout)[idx] = __float2bfloat16(a);
                } else if constexpr (MODE == 2) {
                    a *= __bfloat162float(((const bf16*)aux)[idx]);
                    ((bf16*)Cout)[idx] = __float2bfloat16(a);
                } else {
                    ((float*)Cout)[idx] = a + ((const float*)aux)[idx];
                }
            }
        }
    }
}

// ---------------------------------------------------------------- flash attention (GQA 32q/8kv heads, HD=128)
// Q: [B*QL, 4096] bf16 (rope'd), K/V: [B*KVL, 1024] bf16 (K rope'd), mask: [B,KVL] f32
// O: [B*QL, 4096] bf16.  grid = (QL/64, NH, B), block = 256 (4 waves x 16 q-rows)
__global__ __launch_bounds__(256) void attn_kernel(
    const bf16* __restrict__ Q, const bf16* __restrict__ Kb, const bf16* __restrict__ Vb,
    const float* __restrict__ mask, bf16* __restrict__ O)
{
    const int QL_ = 1024, KVL_ = 2048;
    const float scale = 0.08838834764831845f;  // 1/sqrt(128)
    int qt = blockIdx.x, h = blockIdx.y, b = blockIdx.z;
    int t = threadIdx.x, wave = t >> 6, lane = t & 63;
    int lr = lane & 15, lg = lane >> 4;
    int g = h >> 2;
    __shared__ bf16 Ksm[64 * 128];     // [kv][d]
    __shared__ bf16 Vsm[128 * 72];     // [d][kv] padded stride 72
    __shared__ bf16 Psm[4][16 * 64];   // per-wave P [q][kv]
    int q0 = qt * 64 + wave * 16;

    const bf16* qptr = Q + (size_t)(b * QL_ + q0 + lr) * 4096 + h * 128;
    bfv8 qf[4];
#pragma unroll
    for (int kc = 0; kc < 4; ++kc) qf[kc] = *(const bfv8*)(qptr + kc * 32 + lg * 8);

    const f32x4 zero4 = { 0.f, 0.f, 0.f, 0.f };
    f32x4 accO[8];
#pragma unroll
    for (int dt = 0; dt < 8; ++dt) accO[dt] = zero4;
    float mrow[4] = { -1e30f, -1e30f, -1e30f, -1e30f };
    float lrow[4] = { 0.f, 0.f, 0.f, 0.f };

    for (int kv0 = 0; kv0 < KVL_; kv0 += 64) {
        // stage K [64][128] via async copy (linear LDS)
#pragma unroll
        for (int p2 = 0; p2 < 4; ++p2) {
            int u = p2 * 256 + t;
            gload_lds16(Kb + (size_t)(b * KVL_ + kv0 + (u >> 4)) * 1024 + g * 128 + (u & 15) * 8,
                        &Ksm[u * 8]);
        }
        // stage V transposed [d][kv] (reg-staged)
#pragma unroll
        for (int p2 = 0; p2 < 4; ++p2) {
            int u = p2 * 256 + t;
            int r = u >> 4, ch = u & 15;
            int4 d4 = *(const int4*)(Vb + (size_t)(b * KVL_ + kv0 + r) * 1024 + g * 128 + ch * 8);
            const bf16* dd = (const bf16*)&d4;
#pragma unroll
            for (int jj = 0; jj < 8; ++jj) Vsm[(ch * 8 + jj) * 72 + r] = dd[jj];
        }
        __syncthreads();

        // S = Q K^T for this wave's 16 q-rows x 64 kv
        f32x4 s[4];
#pragma unroll
        for (int ct = 0; ct < 4; ++ct) {
            s[ct] = zero4;
#pragma unroll
            for (int kc = 0; kc < 4; ++kc) {
                bfv8 kf = *(const bfv8*)&Ksm[(ct * 16 + lr) * 128 + kc * 32 + lg * 8];
                s[ct] = mfma16(qf[kc], kf, s[ct]);
            }
            float mv = mask[(size_t)b * KVL_ + kv0 + ct * 16 + lr];
            mv = (mv != 0.f) ? 1.f : 0.f;
#pragma unroll
            for (int i = 0; i < 4; ++i) s[ct][i] = s[ct][i] * scale + mv;
        }

        // online softmax; lane holds rows lg*4+i, col lr of each ct tile
        float rmx[4], mnew[4], corr[4], psum[4];
#pragma unroll
        for (int i = 0; i < 4; ++i) {
            rmx[i] = fmaxf(fmaxf(s[0][i], s[1][i]), fmaxf(s[2][i], s[3][i]));
#pragma unroll
            for (int d = 1; d < 16; d <<= 1) rmx[i] = fmaxf(rmx[i], __shfl_xor(rmx[i], d));
            mnew[i] = fmaxf(mrow[i], rmx[i]);
            corr[i] = expf(mrow[i] - mnew[i]);
            psum[i] = 0.f;
        }
#pragma unroll
        for (int ct = 0; ct < 4; ++ct)
#pragma unroll
            for (int i = 0; i < 4; ++i) {
                float pv = expf(s[ct][i] - mnew[i]);
                psum[i] += pv;
                Psm[wave][(lg * 4 + i) * 64 + ct * 16 + lr] = __float2bfloat16(pv);
            }
#pragma unroll
        for (int i = 0; i < 4; ++i) {
#pragma unroll
            for (int d = 1; d < 16; d <<= 1) psum[i] += __shfl_xor(psum[i], d);
            lrow[i] = lrow[i] * corr[i] + psum[i];
            mrow[i] = mnew[i];
        }
#pragma unroll
        for (int dt = 0; dt < 8; ++dt)
#pragma unroll
            for (int i = 0; i < 4; ++i) accO[dt][i] *= corr[i];
        __syncthreads();  // P visible; all waves done with Ksm

        // O += P V
        bfv8 pf0 = *(const bfv8*)&Psm[wave][lr * 64 + 0 * 32 + lg * 8];
        bfv8 pf1 = *(const bfv8*)&Psm[wave][lr * 64 + 1 * 32 + lg * 8];
#pragma unroll
        for (int dt = 0; dt < 8; ++dt) {
            bfv8 vf0 = *(const bfv8*)&Vsm[(dt * 16 + lr) * 72 + 0 * 32 + lg * 8];
            bfv8 vf1 = *(const bfv8*)&Vsm[(dt * 16 + lr) * 72 + 1 * 32 + lg * 8];
            accO[dt] = mfma16(pf0, vf0, accO[dt]);
            accO[dt] = mfma16(pf1, vf1, accO[dt]);
        }
        __syncthreads();  // done reading Vsm/Psm before next stage
    }

    float invl[4];
#pragma unroll
    for (int i = 0; i < 4; ++i) invl[i] = 1.f / lrow[i];
#pragma unroll
    for (int dt = 0; dt < 8; ++dt)
#pragma unroll
        for (int i = 0; i < 4; ++i)
            O[(size_t)(b * QL_ + q0 + lg * 4 + i) * 4096 + h * 128 + dt * 16 + lr] =
                __float2bfloat16(accO[dt][i] * invl[i]);
}

// ---------------------------------------------------------------- launch
extern "C" void kernel_launch(void* const* d_in, const int* in_sizes, int n_in,
                              void* d_out, int out_size, void* d_ws, size_t ws_size,
                              hipStream_t stream) {
    const float* hidden = (const float*)d_in[0];
    const float* enc    = (const float*)d_in[1];
    const float* mask   = (const float*)d_in[2];
    const float* ln1w   = (const float*)d_in[3];
    const float* ln1b   = (const float*)d_in[4];
    const float* qw     = (const float*)d_in[5];
    const float* kw     = (const float*)d_in[6];
    const float* vw     = (const float*)d_in[7];
    const float* ow     = (const float*)d_in[8];
    const float* ln2w   = (const float*)d_in[9];
    const float* ln2b   = (const float*)d_in[10];
    const float* gatew  = (const float*)d_in[11];
    const float* upw    = (const float*)d_in[12];
    const float* downw  = (const float*)d_in[13];
    float* out = (float*)d_out;

    char* ws = (char*)d_ws;
    bf16*  wbuf  = (bf16*)(ws);                       // 134,217,728 B (max weight: 16384x4096 bf16)
    bf16*  h1    = (bf16*)(ws + 134217728);           // 16,777,216
    bf16*  encb  = (bf16*)(ws + 150994944);           // 33,554,432
    bf16*  qb    = (bf16*)(ws + 184549376);           // 16,777,216
    bf16*  kb    = (bf16*)(ws + 201326592);           // 8,388,608
    bf16*  vb    = (bf16*)(ws + 209715200);           // 8,388,608
    bf16*  attno = (bf16*)(ws + 218103808);           // 16,777,216
    float* h2    = (float*)(ws + 234881024);          // 33,554,432
    bf16*  h2n   = (bf16*)(ws + 268435456);           // 16,777,216
    bf16*  g1    = (bf16*)(ws + 285212672);           // 67,108,864  (total 352,321,536)

    auto cvt = [&](const float* src, bf16* dst, long n) {
        cvt_kernel<<<(int)(n / 2048), 256, 0, stream>>>(src, dst, n / 8);
    };

    // encoder hidden -> bf16; LN1(hidden) -> bf16
    cvt(enc, encb, 16777216L);
    layernorm_kernel<<<2048, 256, 0, stream>>>(hidden, ln1w, ln1b, h1);

    // Q = h1 x qw^T  [2048, 4096]; rope over QL=1024, 32 heads
    cvt(qw, wbuf, 16777216L);
    gemm_bt<0><<<dim3(32, 16), 256, 0, stream>>>(h1, wbuf, qb, nullptr, 2048, 4096, 4096);
    rope_kernel<<<16384, 256, 0, stream>>>(qb, 32, 1024, 2048L * 32 * 64);

    // K = encb x kw^T  [4096, 1024]; rope over KVL=2048, 8 heads
    cvt(kw, wbuf, 4194304L);
    gemm_bt<0><<<dim3(8, 32), 256, 0, stream>>>(encb, wbuf, kb, nullptr, 4096, 1024, 4096);
    rope_kernel<<<8192, 256, 0, stream>>>(kb, 8, 2048, 4096L * 8 * 64);

    // V = encb x vw^T  [4096, 1024]
    cvt(vw, wbuf, 4194304L);
    gemm_bt<0><<<dim3(8, 32), 256, 0, stream>>>(encb, wbuf, vb, nullptr, 4096, 1024, 4096);

    // attention
    attn_kernel<<<dim3(16, 32, 2), 256, 0, stream>>>(qb, kb, vb, mask, attno);

    // h2 = hidden + attno x ow^T (fp32)
    cvt(ow, wbuf, 16777216L);
    gemm_bt<3><<<dim3(32, 16), 256, 0, stream>>>(attno, wbuf, h2, hidden, 2048, 4096, 4096);

    // LN2 -> bf16
    layernorm_kernel<<<2048, 256, 0, stream>>>(h2, ln2w, ln2b, h2n);

    // g1 = silu(h2n x gatew^T); g1 *= h2n x upw^T
    cvt(gatew, wbuf, 67108864L);
    gemm_bt<1><<<dim3(128, 16), 256, 0, stream>>>(h2n, wbuf, g1, nullptr, 2048, 16384, 4096);
    cvt(upw, wbuf, 67108864L);
    gemm_bt<2><<<dim3(128, 16), 256, 0, stream>>>(h2n, wbuf, g1, g1, 2048, 16384, 4096);

    // out = h2 + g1 x downw^T (fp32)
    cvt(downw, wbuf, 67108864L);
    gemm_bt<3><<<dim3(32, 16), 256, 0, stream>>>(g1, wbuf, out, h2, 2048, 4096, 16384);
}

// Round 2
// 1924.907 us; speedup vs baseline: 1.1903x; 1.1903x over previous
//
#include <hip/hip_runtime.h>
#include <hip/hip_bf16.h>
#include <math.h>

using bf16 = __hip_bfloat16;
typedef __bf16 bfv8 __attribute__((ext_vector_type(8)));
typedef float f32x4 __attribute__((ext_vector_type(4)));

__device__ __forceinline__ f32x4 mfma16(bfv8 a, bfv8 b, f32x4 c) {
    return __builtin_amdgcn_mfma_f32_16x16x32_bf16(a, b, c, 0, 0, 0);
}

__device__ __forceinline__ void gload_lds16(const void* g, void* l) {
    __builtin_amdgcn_global_load_lds(
        (const __attribute__((address_space(1))) void*)g,
        (__attribute__((address_space(3))) void*)l, 16, 0, 0);
}

// ---------------------------------------------------------------- cvt f32->bf16
__global__ void cvt_kernel(const float* __restrict__ in, bf16* __restrict__ out, long n8) {
    long u = (long)blockIdx.x * 256 + threadIdx.x;
    if (u >= n8) return;
    const float4* p = (const float4*)in + u * 2;
    float4 a = p[0], b = p[1];
    bf16 t8[8] = { __float2bfloat16(a.x), __float2bfloat16(a.y), __float2bfloat16(a.z), __float2bfloat16(a.w),
                   __float2bfloat16(b.x), __float2bfloat16(b.y), __float2bfloat16(b.z), __float2bfloat16(b.w) };
    *(int4*)(out + u * 8) = *(const int4*)t8;
}

// ---------------------------------------------------------------- layernorm (D=4096), fp32 in -> bf16 out
__global__ void layernorm_kernel(const float* __restrict__ x, const float* __restrict__ gw,
                                 const float* __restrict__ gb, bf16* __restrict__ out)
{
    const int D = 4096;
    int row = blockIdx.x, t = threadIdx.x;
    const float4* xr = (const float4*)(x + (size_t)row * D);
    float4 v[4];
    float s1 = 0.f, s2 = 0.f;
#pragma unroll
    for (int j = 0; j < 4; ++j) {
        v[j] = xr[t + j * 256];
        s1 += v[j].x + v[j].y + v[j].z + v[j].w;
        s2 += v[j].x * v[j].x + v[j].y * v[j].y + v[j].z * v[j].z + v[j].w * v[j].w;
    }
#pragma unroll
    for (int d = 1; d < 64; d <<= 1) { s1 += __shfl_xor(s1, d); s2 += __shfl_xor(s2, d); }
    __shared__ float red[8];
    int wave = t >> 6, lane = t & 63;
    if (lane == 0) { red[wave] = s1; red[4 + wave] = s2; }
    __syncthreads();
    s1 = red[0] + red[1] + red[2] + red[3];
    s2 = red[4] + red[5] + red[6] + red[7];
    float mu = s1 * (1.f / 4096.f);
    float var = s2 * (1.f / 4096.f) - mu * mu;
    float rs = rsqrtf(var + 1e-5f);
    bf16* orow = out + (size_t)row * D;
#pragma unroll
    for (int j = 0; j < 4; ++j) {
        int base = (t + j * 256) * 4;
        float xs[4] = { v[j].x, v[j].y, v[j].z, v[j].w };
        bf16 o4[4];
#pragma unroll
        for (int c = 0; c < 4; ++c)
            o4[c] = __float2bfloat16((xs[c] - mu) * rs * gw[base + c] + gb[base + c]);
        *(int2*)(orow + base) = *(const int2*)o4;
    }
}

// ---------------------------------------------------------------- RoPE in-place on bf16 [rows, nheads*128]
__global__ void rope_kernel(bf16* __restrict__ x, int nheads, int seqlen, long total) {
    long idx = (long)blockIdx.x * 256 + threadIdx.x;
    if (idx >= total) return;
    int j = (int)(idx & 63);
    long t2 = idx >> 6;
    int h = (int)(t2 % nheads);
    long row = t2 / nheads;
    int pos = (int)(row % seqlen);
    float inv = exp2f(-(float)j * 0.20762050593046015f);  // log2(10000)/64
    float ang = (float)pos * inv;
    float s, c;
    sincosf(ang, &s, &c);
    bf16* p = x + row * ((long)nheads * 128) + (long)h * 128 + j;
    float x0 = __bfloat162float(p[0]);
    float x1 = __bfloat162float(p[64]);
    p[0]  = __float2bfloat16(x0 * c - x1 * s);
    p[64] = __float2bfloat16(x1 * c + x0 * s);
}

// ---------------------------------------------------------------- old 128x128 GEMM (kept for k/v proj)
template<int MODE>
__global__ void gemm_bt(const bf16* __restrict__ A, const bf16* __restrict__ W,
                        void* __restrict__ Cout, const void* __restrict__ aux,
                        int M, int N, int K)
{
    __shared__ bf16 Asm[128 * 32];
    __shared__ bf16 Bsm[128 * 32];
    const int t = threadIdx.x;
    const int wave = t >> 6, lane = t & 63;
    const int lr = lane & 15, lg = lane >> 4;
    const int wr = wave >> 1, wc = wave & 1;
    const int bm = blockIdx.y * 128, bn = blockIdx.x * 128;

    const f32x4 zero4 = { 0.f, 0.f, 0.f, 0.f };
    f32x4 acc[4][4];
#pragma unroll
    for (int m = 0; m < 4; ++m)
#pragma unroll
        for (int n = 0; n < 4; ++n) acc[m][n] = zero4;

    for (int k0 = 0; k0 < K; k0 += 32) {
#pragma unroll
        for (int p = 0; p < 2; ++p) {
            int u = p * 256 + t;
            int row = u >> 2, ch = u & 3;
            gload_lds16(A + (size_t)(bm + row) * K + k0 + ch * 8, &Asm[u * 8]);
            gload_lds16(W + (size_t)(bn + row) * K + k0 + ch * 8, &Bsm[u * 8]);
        }
        __syncthreads();
        bfv8 af[4], bfm[4];
#pragma unroll
        for (int m = 0; m < 4; ++m) af[m] = *(const bfv8*)&Asm[(wr * 64 + m * 16 + lr) * 32 + lg * 8];
#pragma unroll
        for (int n = 0; n < 4; ++n) bfm[n] = *(const bfv8*)&Bsm[(wc * 64 + n * 16 + lr) * 32 + lg * 8];
#pragma unroll
        for (int m = 0; m < 4; ++m)
#pragma unroll
            for (int n = 0; n < 4; ++n)
                acc[m][n] = mfma16(af[m], bfm[n], acc[m][n]);
        __syncthreads();
    }

    const int r0 = bm + wr * 64, c0 = bn + wc * 64;
#pragma unroll
    for (int m = 0; m < 4; ++m)
#pragma unroll
        for (int n = 0; n < 4; ++n)
#pragma unroll
            for (int i = 0; i < 4; ++i) {
                int r = r0 + m * 16 + lg * 4 + i;
                int c = c0 + n * 16 + lr;
                size_t idx = (size_t)r * N + c;
                float a = acc[m][n][i];
                if constexpr (MODE == 0) ((bf16*)Cout)[idx] = __float2bfloat16(a);
                else ((float*)Cout)[idx] = a + ((const float*)aux)[idx];
            }
}

// ---------------------------------------------------------------- pipelined 256x128 GEMM, BK=32, 3-buf LDS
// C[M,N] = A[M,K] x W[N,K]^T. 512 thr = 8 waves (2M x 4N), per-wave 128x32.
// LDS swizzle (64B rows): phys = U ^ ((row&3)<<4)  [involution, row-preserving]
// Ledger: compute buf[t%3]; stage t+2 -> buf[(t+2)%3]; trailing s_waitcnt vmcnt(3).
template<int MODE>
__global__ __launch_bounds__(512, 2) void gemm256(const bf16* __restrict__ A, const bf16* __restrict__ W,
        void* __restrict__ Cout, const void* __restrict__ aux, int M, int N, int K)
{
    __shared__ bf16 lds[3][(256 + 128) * 32];   // per buf: A 8192 el (16KB) + B 4096 el (8KB)
    const int t = threadIdx.x;
    const int wid = t >> 6, lane = t & 63;
    const int lr = lane & 15, lg = lane >> 4;
    const int wr = wid >> 2, wc = wid & 3;
    // XCD-aware block swizzle (nwg % 8 == 0 at all call sites)
    const int gx = gridDim.x;
    const int nwg = gx * gridDim.y;
    const int bid0 = blockIdx.y * gx + blockIdx.x;
    const int rebid = (bid0 & 7) * (nwg >> 3) + (bid0 >> 3);
    const int bm = (rebid / gx) * 256, bn = (rebid % gx) * 128;

    auto stage = [&](int tt, int buf) {
        const int k0 = tt * 32;
#pragma unroll
        for (int c = 0; c < 2; ++c) {           // A half: 2 x 16B per thread
            int Wb = (t + c * 512) * 16;
            int row = Wb >> 6;
            int col = ((Wb & 63) ^ ((row & 3) << 4)) >> 1;
            gload_lds16(A + (size_t)(bm + row) * K + k0 + col, &lds[buf][Wb >> 1]);
        }
        {                                        // B half: 1 x 16B per thread
            int Wb = t * 16;
            int row = Wb >> 6;
            int col = ((Wb & 63) ^ ((row & 3) << 4)) >> 1;
            gload_lds16(W + (size_t)(bn + row) * K + k0 + col, &lds[buf][8192 + (Wb >> 1)]);
        }
    };

    const f32x4 zero4 = { 0.f, 0.f, 0.f, 0.f };
    f32x4 acc[8][2];
#pragma unroll
    for (int m = 0; m < 8; ++m) { acc[m][0] = zero4; acc[m][1] = zero4; }

    const int T = K >> 5;
    stage(0, 0);
    stage(1, 1);
    asm volatile("s_waitcnt vmcnt(3)" ::: "memory");
    __builtin_amdgcn_s_barrier();
    __builtin_amdgcn_sched_barrier(0);

    for (int tt = 0; tt < T; ++tt) {
        const int buf = tt % 3;
        bfv8 af[8], bfr[2];
#pragma unroll
        for (int m = 0; m < 8; ++m) {
            int row = wr * 128 + m * 16 + lr;
            int U = row * 64 + lg * 16;
            af[m] = *(const bfv8*)((const char*)&lds[buf][0] + (U ^ ((row & 3) << 4)));
        }
#pragma unroll
        for (int n = 0; n < 2; ++n) {
            int row = wc * 32 + n * 16 + lr;
            int U = row * 64 + lg * 16;
            bfr[n] = *(const bfv8*)((const char*)&lds[buf][8192] + (U ^ ((row & 3) << 4)));
        }
        if (tt + 2 < T) stage(tt + 2, (tt + 2) % 3);
        __builtin_amdgcn_s_barrier();
        __builtin_amdgcn_sched_barrier(0);
        __builtin_amdgcn_s_setprio(1);
#pragma unroll
        for (int m = 0; m < 8; ++m) {
            acc[m][0] = mfma16(af[m], bfr[0], acc[m][0]);
            acc[m][1] = mfma16(af[m], bfr[1], acc[m][1]);
        }
        __builtin_amdgcn_s_setprio(0);
        if (tt + 2 < T) { asm volatile("s_waitcnt vmcnt(3)" ::: "memory"); }
        else           { asm volatile("s_waitcnt vmcnt(0)" ::: "memory"); }
        __builtin_amdgcn_s_barrier();
        __builtin_amdgcn_sched_barrier(0);
    }

    const int r0 = bm + wr * 128, c0 = bn + wc * 32;
#pragma unroll
    for (int m = 0; m < 8; ++m)
#pragma unroll
        for (int n = 0; n < 2; ++n)
#pragma unroll
            for (int i = 0; i < 4; ++i) {
                int r = r0 + m * 16 + lg * 4 + i;
                int c = c0 + n * 16 + lr;
                size_t idx = (size_t)r * N + c;
                float a = acc[m][n][i];
                if constexpr (MODE == 0) {
                    ((bf16*)Cout)[idx] = __float2bfloat16(a);
                } else if constexpr (MODE == 1) {
                    a = a / (1.f + expf(-a));
                    ((bf16*)Cout)[idx] = __float2bfloat16(a);
                } else if constexpr (MODE == 2) {
                    a *= __bfloat162float(((const bf16*)aux)[idx]);
                    ((bf16*)Cout)[idx] = __float2bfloat16(a);
                } else {
                    ((float*)Cout)[idx] = a + ((const float*)aux)[idx];
                }
            }
}

// ---------------------------------------------------------------- V transpose: vb[(b*2048+kv)][1024] -> vt[(b*1024+col)][2048]
__global__ void transpose_v(const bf16* __restrict__ vb, bf16* __restrict__ vt) {
    __shared__ bf16 tile[64][68];
    int kv0 = blockIdx.x * 64, c0 = blockIdx.y * 64, b = blockIdx.z;
    int t = threadIdx.x;
    int cr = t & 15, rr = t >> 4;
#pragma unroll
    for (int j = 0; j < 4; ++j) {
        int r = rr + j * 16;
        *(int2*)&tile[r][cr * 4] = *(const int2*)&vb[(size_t)(b * 2048 + kv0 + r) * 1024 + c0 + cr * 4];
    }
    __syncthreads();
#pragma unroll
    for (int j = 0; j < 4; ++j) {
        int cc = rr + j * 16;
        bf16 tmp[4];
#pragma unroll
        for (int q = 0; q < 4; ++q) tmp[q] = tile[cr * 4 + q][cc];
        *(int2*)&vt[(size_t)(b * 1024 + c0 + cc) * 2048 + kv0 + cr * 4] = *(const int2*)tmp;
    }
}

// ---------------------------------------------------------------- flash attention v2 (GQA 32q/8kv, HD=128)
// Q: [B*QL,4096] bf16 rope'd; K: [B*KVL,1024] bf16 rope'd; Vt: [(b*8+g)*128+d][2048] bf16
// K/Vt tiles staged via global_load_lds with XOR swizzle byte^=((row&7)<<4) on both sides.
__global__ __launch_bounds__(256) void attn_kernel(
    const bf16* __restrict__ Q, const bf16* __restrict__ Kb, const bf16* __restrict__ Vt,
    const float* __restrict__ mask, bf16* __restrict__ O)
{
    const int QL_ = 1024, KVL_ = 2048;
    const float scale = 0.08838834764831845f;  // 1/sqrt(128)
    int qt = blockIdx.x, h = blockIdx.y, b = blockIdx.z;
    int t = threadIdx.x, wave = t >> 6, lane = t & 63;
    int lr = lane & 15, lg = lane >> 4;
    int g = h >> 2;
    __shared__ bf16 Ksm[64 * 128];     // [kv][d], 256B rows, swizzled
    __shared__ bf16 Vsm[128 * 64];     // [d][kv], 128B rows, swizzled
    __shared__ bf16 Psm[4][16 * 72];   // per-wave P [q][kv], stride 72
    int q0 = qt * 64 + wave * 16;

    const bf16* qptr = Q + (size_t)(b * QL_ + q0 + lr) * 4096 + h * 128;
    bfv8 qf[4];
#pragma unroll
    for (int kc = 0; kc < 4; ++kc) qf[kc] = *(const bfv8*)(qptr + kc * 32 + lg * 8);

    const f32x4 zero4 = { 0.f, 0.f, 0.f, 0.f };
    f32x4 accO[8];
#pragma unroll
    for (int dt = 0; dt < 8; ++dt) accO[dt] = zero4;
    float mrow[4] = { -1e30f, -1e30f, -1e30f, -1e30f };
    float lrow[4] = { 0.f, 0.f, 0.f, 0.f };

    for (int kv0 = 0; kv0 < KVL_; kv0 += 64) {
        // stage K [64][128]: linear dest, inverse-swizzled source
#pragma unroll
        for (int p2 = 0; p2 < 4; ++p2) {
            int Wb = (p2 * 256 + t) * 16;
            int row = Wb >> 8;
            int col = ((Wb & 255) ^ ((row & 7) << 4)) >> 1;
            gload_lds16(Kb + (size_t)(b * KVL_ + kv0 + row) * 1024 + g * 128 + col,
                        (char*)Ksm + Wb);
        }
        // stage Vt tile [128][64]: rows = d, cols = kv
#pragma unroll
        for (int p2 = 0; p2 < 4; ++p2) {
            int Wb = (p2 * 256 + t) * 16;
            int row = Wb >> 7;
            int col = ((Wb & 127) ^ ((row & 7) << 4)) >> 1;
            gload_lds16(Vt + (size_t)(b * 1024 + g * 128 + row) * 2048 + kv0 + col,
                        (char*)Vsm + Wb);
        }
        __syncthreads();

        // S = Q K^T for this wave's 16 q-rows x 64 kv
        f32x4 s[4];
#pragma unroll
        for (int ct = 0; ct < 4; ++ct) {
            s[ct] = zero4;
#pragma unroll
            for (int kc = 0; kc < 4; ++kc) {
                int row = ct * 16 + lr;
                int U = row * 256 + kc * 64 + lg * 16;
                bfv8 kf = *(const bfv8*)((const char*)Ksm + (U ^ ((row & 7) << 4)));
                s[ct] = mfma16(qf[kc], kf, s[ct]);
            }
            float mv = mask[(size_t)b * KVL_ + kv0 + ct * 16 + lr];
            mv = (mv != 0.f) ? 1.f : 0.f;
#pragma unroll
            for (int i = 0; i < 4; ++i) s[ct][i] = s[ct][i] * scale + mv;
        }

        // online softmax
        float rmx[4], mnew[4], corr[4], psum[4];
#pragma unroll
        for (int i = 0; i < 4; ++i) {
            rmx[i] = fmaxf(fmaxf(s[0][i], s[1][i]), fmaxf(s[2][i], s[3][i]));
#pragma unroll
            for (int d = 1; d < 16; d <<= 1) rmx[i] = fmaxf(rmx[i], __shfl_xor(rmx[i], d));
            mnew[i] = fmaxf(mrow[i], rmx[i]);
            corr[i] = expf(mrow[i] - mnew[i]);
            psum[i] = 0.f;
        }
#pragma unroll
        for (int ct = 0; ct < 4; ++ct)
#pragma unroll
            for (int i = 0; i < 4; ++i) {
                float pv = expf(s[ct][i] - mnew[i]);
                psum[i] += pv;
                Psm[wave][(lg * 4 + i) * 72 + ct * 16 + lr] = __float2bfloat16(pv);
            }
#pragma unroll
        for (int i = 0; i < 4; ++i) {
#pragma unroll
            for (int d = 1; d < 16; d <<= 1) psum[i] += __shfl_xor(psum[i], d);
            lrow[i] = lrow[i] * corr[i] + psum[i];
            mrow[i] = mnew[i];
        }
#pragma unroll
        for (int dt = 0; dt < 8; ++dt)
#pragma unroll
            for (int i = 0; i < 4; ++i) accO[dt][i] *= corr[i];
        __syncthreads();  // P visible

        // O += P V
        bfv8 pf0 = *(const bfv8*)&Psm[wave][lr * 72 + 0 * 32 + lg * 8];
        bfv8 pf1 = *(const bfv8*)&Psm[wave][lr * 72 + 1 * 32 + lg * 8];
#pragma unroll
        for (int dt = 0; dt < 8; ++dt) {
            int row = dt * 16 + lr;
            int U0 = row * 128 + 0 * 64 + lg * 16;
            int U1 = row * 128 + 1 * 64 + lg * 16;
            bfv8 vf0 = *(const bfv8*)((const char*)Vsm + (U0 ^ ((row & 7) << 4)));
            bfv8 vf1 = *(const bfv8*)((const char*)Vsm + (U1 ^ ((row & 7) << 4)));
            accO[dt] = mfma16(pf0, vf0, accO[dt]);
            accO[dt] = mfma16(pf1, vf1, accO[dt]);
        }
        __syncthreads();  // done reading Vsm/Psm before next stage
    }

    float invl[4];
#pragma unroll
    for (int i = 0; i < 4; ++i) invl[i] = 1.f / lrow[i];
#pragma unroll
    for (int dt = 0; dt < 8; ++dt)
#pragma unroll
        for (int i = 0; i < 4; ++i)
            O[(size_t)(b * QL_ + q0 + lg * 4 + i) * 4096 + h * 128 + dt * 16 + lr] =
                __float2bfloat16(accO[dt][i] * invl[i]);
}

// ---------------------------------------------------------------- launch
extern "C" void kernel_launch(void* const* d_in, const int* in_sizes, int n_in,
                              void* d_out, int out_size, void* d_ws, size_t ws_size,
                              hipStream_t stream) {
    const float* hidden = (const float*)d_in[0];
    const float* enc    = (const float*)d_in[1];
    const float* mask   = (const float*)d_in[2];
    const float* ln1w   = (const float*)d_in[3];
    const float* ln1b   = (const float*)d_in[4];
    const float* qw     = (const float*)d_in[5];
    const float* kw     = (const float*)d_in[6];
    const float* vw     = (const float*)d_in[7];
    const float* ow     = (const float*)d_in[8];
    const float* ln2w   = (const float*)d_in[9];
    const float* ln2b   = (const float*)d_in[10];
    const float* gatew  = (const float*)d_in[11];
    const float* upw    = (const float*)d_in[12];
    const float* downw  = (const float*)d_in[13];
    float* out = (float*)d_out;

    char* ws = (char*)d_ws;
    bf16*  wbuf  = (bf16*)(ws);                       // 134,217,728 B
    bf16*  h1    = (bf16*)(ws + 134217728);           // 16,777,216
    bf16*  encb  = (bf16*)(ws + 150994944);           // 33,554,432
    bf16*  qb    = (bf16*)(ws + 184549376);           // 16,777,216
    bf16*  kb    = (bf16*)(ws + 201326592);           // 8,388,608
    bf16*  vb    = (bf16*)(ws + 209715200);           // 8,388,608
    bf16*  attno = (bf16*)(ws + 218103808);           // 16,777,216
    float* h2    = (float*)(ws + 234881024);          // 33,554,432 (vt lives here pre-o-proj)
    bf16*  vt    = (bf16*)(ws + 234881024);           // 8,388,608 (aliases h2; dead before o-proj writes)
    bf16*  h2n   = (bf16*)(ws + 268435456);           // 16,777,216
    bf16*  g1    = (bf16*)(ws + 285212672);           // 67,108,864

    auto cvt = [&](const float* src, bf16* dst, long n) {
        cvt_kernel<<<(int)(n / 2048), 256, 0, stream>>>(src, dst, n / 8);
    };

    // encoder hidden -> bf16; LN1(hidden) -> bf16
    cvt(enc, encb, 16777216L);
    layernorm_kernel<<<2048, 256, 0, stream>>>(hidden, ln1w, ln1b, h1);

    // Q = h1 x qw^T  [2048, 4096]; rope
    cvt(qw, wbuf, 16777216L);
    gemm256<0><<<dim3(32, 8), 512, 0, stream>>>(h1, wbuf, qb, nullptr, 2048, 4096, 4096);
    rope_kernel<<<16384, 256, 0, stream>>>(qb, 32, 1024, 2048L * 32 * 64);

    // K = encb x kw^T  [4096, 1024]; rope
    cvt(kw, wbuf, 4194304L);
    gemm_bt<0><<<dim3(8, 32), 256, 0, stream>>>(encb, wbuf, kb, nullptr, 4096, 1024, 4096);
    rope_kernel<<<8192, 256, 0, stream>>>(kb, 8, 2048, 4096L * 8 * 64);

    // V = encb x vw^T  [4096, 1024]; transpose to vt
    cvt(vw, wbuf, 4194304L);
    gemm_bt<0><<<dim3(8, 32), 256, 0, stream>>>(encb, wbuf, vb, nullptr, 4096, 1024, 4096);
    transpose_v<<<dim3(32, 16, 2), 256, 0, stream>>>(vb, vt);

    // attention
    attn_kernel<<<dim3(16, 32, 2), 256, 0, stream>>>(qb, kb, vt, mask, attno);

    // h2 = hidden + attno x ow^T (fp32)  [overwrites vt region]
    cvt(ow, wbuf, 16777216L);
    gemm256<3><<<dim3(32, 8), 512, 0, stream>>>(attno, wbuf, h2, hidden, 2048, 4096, 4096);

    // LN2 -> bf16
    layernorm_kernel<<<2048, 256, 0, stream>>>(h2, ln2w, ln2b, h2n);

    // g1 = silu(h2n x gatew^T); g1 *= h2n x upw^T
    cvt(gatew, wbuf, 67108864L);
    gemm256<1><<<dim3(128, 8), 512, 0, stream>>>(h2n, wbuf, g1, nullptr, 2048, 16384, 4096);
    cvt(upw, wbuf, 67108864L);
    gemm256<2><<<dim3(128, 8), 512, 0, stream>>>(h2n, wbuf, g1, g1, 2048, 16384, 4096);

    // out = h2 + g1 x downw^T (fp32)
    cvt(downw, wbuf, 67108864L);
    gemm256<3><<<dim3(32, 8), 512, 0, stream>>>(g1, wbuf, out, h2, 2048, 4096, 16384);
}

// Round 3
// 1839.611 us; speedup vs baseline: 1.2455x; 1.0464x over previous
//
#include <hip/hip_runtime.h>
#include <hip/hip_bf16.h>
#include <math.h>

using bf16 = __hip_bfloat16;
typedef __bf16 bfv8 __attribute__((ext_vector_type(8)));
typedef float f32x4 __attribute__((ext_vector_type(4)));

__device__ __forceinline__ f32x4 mfma16(bfv8 a, bfv8 b, f32x4 c) {
    return __builtin_amdgcn_mfma_f32_16x16x32_bf16(a, b, c, 0, 0, 0);
}

__device__ __forceinline__ void gload_lds16(const void* g, void* l) {
    __builtin_amdgcn_global_load_lds(
        (const __attribute__((address_space(1))) void*)g,
        (__attribute__((address_space(3))) void*)l, 16, 0, 0);
}

// ---------------------------------------------------------------- cvt f32->bf16
__global__ void cvt_kernel(const float* __restrict__ in, bf16* __restrict__ out, long n8) {
    long u = (long)blockIdx.x * 256 + threadIdx.x;
    if (u >= n8) return;
    const float4* p = (const float4*)in + u * 2;
    float4 a = p[0], b = p[1];
    bf16 t8[8] = { __float2bfloat16(a.x), __float2bfloat16(a.y), __float2bfloat16(a.z), __float2bfloat16(a.w),
                   __float2bfloat16(b.x), __float2bfloat16(b.y), __float2bfloat16(b.z), __float2bfloat16(b.w) };
    *(int4*)(out + u * 8) = *(const int4*)t8;
}

// ---------------------------------------------------------------- layernorm (D=4096), fp32 in -> bf16 out
__global__ void layernorm_kernel(const float* __restrict__ x, const float* __restrict__ gw,
                                 const float* __restrict__ gb, bf16* __restrict__ out)
{
    const int D = 4096;
    int row = blockIdx.x, t = threadIdx.x;
    const float4* xr = (const float4*)(x + (size_t)row * D);
    float4 v[4];
    float s1 = 0.f, s2 = 0.f;
#pragma unroll
    for (int j = 0; j < 4; ++j) {
        v[j] = xr[t + j * 256];
        s1 += v[j].x + v[j].y + v[j].z + v[j].w;
        s2 += v[j].x * v[j].x + v[j].y * v[j].y + v[j].z * v[j].z + v[j].w * v[j].w;
    }
#pragma unroll
    for (int d = 1; d < 64; d <<= 1) { s1 += __shfl_xor(s1, d); s2 += __shfl_xor(s2, d); }
    __shared__ float red[8];
    int wave = t >> 6, lane = t & 63;
    if (lane == 0) { red[wave] = s1; red[4 + wave] = s2; }
    __syncthreads();
    s1 = red[0] + red[1] + red[2] + red[3];
    s2 = red[4] + red[5] + red[6] + red[7];
    float mu = s1 * (1.f / 4096.f);
    float var = s2 * (1.f / 4096.f) - mu * mu;
    float rs = rsqrtf(var + 1e-5f);
    bf16* orow = out + (size_t)row * D;
#pragma unroll
    for (int j = 0; j < 4; ++j) {
        int base = (t + j * 256) * 4;
        float xs[4] = { v[j].x, v[j].y, v[j].z, v[j].w };
        bf16 o4[4];
#pragma unroll
        for (int c = 0; c < 4; ++c)
            o4[c] = __float2bfloat16((xs[c] - mu) * rs * gw[base + c] + gb[base + c]);
        *(int2*)(orow + base) = *(const int2*)o4;
    }
}

// ---------------------------------------------------------------- RoPE in-place on bf16 [rows, nheads*128]
__global__ void rope_kernel(bf16* __restrict__ x, int nheads, int seqlen, long total) {
    long idx = (long)blockIdx.x * 256 + threadIdx.x;
    if (idx >= total) return;
    int j = (int)(idx & 63);
    long t2 = idx >> 6;
    int h = (int)(t2 % nheads);
    long row = t2 / nheads;
    int pos = (int)(row % seqlen);
    float inv = exp2f(-(float)j * 0.20762050593046015f);  // log2(10000)/64
    float ang = (float)pos * inv;
    float s, c;
    sincosf(ang, &s, &c);
    bf16* p = x + row * ((long)nheads * 128) + (long)h * 128 + j;
    float x0 = __bfloat162float(p[0]);
    float x1 = __bfloat162float(p[64]);
    p[0]  = __float2bfloat16(x0 * c - x1 * s);
    p[64] = __float2bfloat16(x1 * c + x0 * s);
}

// ---------------------------------------------------------------- pipelined GEMM, BK=32, 3-buf LDS
// C[M,N] = A[M,K] x W[N,K]^T. 512 thr = 8 waves (2M x 4N); per-wave (BM/2) x (BN/4).
// LDS pair-swizzle: phys = U ^ (((U>>7)&7)<<4) -- involution, flips bits 4-6 based on
// bits 7-9 => 16-lane column-slice reads of b128 touch each 16B of the 1KB exactly once
// (conflict-free). Applied inverse on global_load_lds source, forward on ds_read.
// Ledger: compute buf[t%3]; stage t+2 -> buf[(t+2)%3] (overwrites t-1, whose reads all
// completed before its end-of-iter barrier); trailing s_waitcnt vmcnt(SLD) keeps tile
// t+2's loads in flight across the barrier (never drains to 0 in steady state).
// MODE 0: bf16; 1: silu->bf16; 2: *aux(bf16)->bf16; 3: +aux(f32)->f32
// DUAL: W rows >= Nsplit come from W2; C cols >= Nsplit go to C2 (both [M,Nsplit]-ish).
template<int BM, int BN, int MODE, bool DUAL>
__global__ __launch_bounds__(512, 2) void gemm_p(
        const bf16* __restrict__ A, const bf16* __restrict__ W, const bf16* __restrict__ W2,
        void* __restrict__ Cout, void* __restrict__ Cout2, const void* __restrict__ aux,
        int M, int N, int K, int Nsplit)
{
    constexpr int MF = BM / 32;           // m-frags per wave
    constexpr int NF = BN / 64;           // n-frags per wave
    constexpr int ALD = BM / 128;         // A stage loads per thread
    constexpr int BLD = BN / 128;         // B stage loads per thread
    constexpr int SLD = ALD + BLD;
    __shared__ bf16 lds[3][(BM + BN) * 32];

    const int t = threadIdx.x;
    const int wid = t >> 6, lane = t & 63;
    const int lr = lane & 15, lg = lane >> 4;
    const int wr = wid >> 2, wc = wid & 3;
    // XCD-aware block swizzle (all call-site grids have nwg % 8 == 0)
    const int gx = gridDim.x;
    const int nwg = gx * gridDim.y;
    const int bid0 = blockIdx.y * gx + blockIdx.x;
    const int rebid = (bid0 & 7) * (nwg >> 3) + (bid0 >> 3);
    const int bm = (rebid / gx) * BM, bn = (rebid % gx) * BN;

    auto stage = [&](int tt, int buf) {
        const int k0 = tt * 32;
        char* ldsA = (char*)&lds[buf][0];
#pragma unroll
        for (int c = 0; c < ALD; ++c) {
            int Wb = (t + c * 512) * 16;
            int L = Wb ^ (((Wb >> 7) & 7) << 4);
            int row = L >> 6, colb = L & 63;
            gload_lds16(A + (size_t)(bm + row) * K + k0 + (colb >> 1), ldsA + Wb);
        }
        char* ldsB = (char*)&lds[buf][BM * 32];
#pragma unroll
        for (int c = 0; c < BLD; ++c) {
            int Wb = (t + c * 512) * 16;
            int L = Wb ^ (((Wb >> 7) & 7) << 4);
            int row = L >> 6, colb = L & 63;
            const bf16* src;
            if constexpr (DUAL) {
                int nr = bn + row;
                src = (nr >= Nsplit) ? W2 + (size_t)(nr - Nsplit) * K + k0 + (colb >> 1)
                                     : W  + (size_t)nr * K + k0 + (colb >> 1);
            } else {
                src = W + (size_t)(bn + row) * K + k0 + (colb >> 1);
            }
            gload_lds16(src, ldsB + Wb);
        }
    };

    const f32x4 zero4 = { 0.f, 0.f, 0.f, 0.f };
    f32x4 acc[MF][NF];
#pragma unroll
    for (int m = 0; m < MF; ++m)
#pragma unroll
        for (int n = 0; n < NF; ++n) acc[m][n] = zero4;

    const int T = K >> 5;
    stage(0, 0);
    stage(1, 1);
    if constexpr (SLD == 4) asm volatile("s_waitcnt vmcnt(4)" ::: "memory");
    else                    asm volatile("s_waitcnt vmcnt(3)" ::: "memory");
    __builtin_amdgcn_s_barrier();
    __builtin_amdgcn_sched_barrier(0);

    for (int tt = 0; tt < T; ++tt) {
        const int buf = tt % 3;
        bfv8 af[MF], bfr[NF];
#pragma unroll
        for (int m = 0; m < MF; ++m) {
            int row = wr * (BM / 2) + m * 16 + lr;
            int U = row * 64 + lg * 16;
            af[m] = *(const bfv8*)((const char*)&lds[buf][0] + (U ^ (((U >> 7) & 7) << 4)));
        }
#pragma unroll
        for (int n = 0; n < NF; ++n) {
            int row = wc * (BN / 4) + n * 16 + lr;
            int U = row * 64 + lg * 16;
            bfr[n] = *(const bfv8*)((const char*)&lds[buf][BM * 32] + (U ^ (((U >> 7) & 7) << 4)));
        }
        if (tt + 2 < T) stage(tt + 2, (tt + 2) % 3);
        __builtin_amdgcn_s_setprio(1);
#pragma unroll
        for (int m = 0; m < MF; ++m)
#pragma unroll
            for (int n = 0; n < NF; ++n)
                acc[m][n] = mfma16(af[m], bfr[n], acc[m][n]);
        __builtin_amdgcn_s_setprio(0);
        if (tt + 2 < T) {
            if constexpr (SLD == 4) asm volatile("s_waitcnt vmcnt(4)" ::: "memory");
            else                    asm volatile("s_waitcnt vmcnt(3)" ::: "memory");
        } else {
            asm volatile("s_waitcnt vmcnt(0)" ::: "memory");
        }
        __builtin_amdgcn_s_barrier();
        __builtin_amdgcn_sched_barrier(0);
    }

    const int r0 = bm + wr * (BM / 2), c0 = bn + wc * (BN / 4);
#pragma unroll
    for (int m = 0; m < MF; ++m)
#pragma unroll
        for (int n = 0; n < NF; ++n)
#pragma unroll
            for (int i = 0; i < 4; ++i) {
                int r = r0 + m * 16 + lg * 4 + i;
                int c = c0 + n * 16 + lr;
                float a = acc[m][n][i];
                if constexpr (DUAL) {
                    if (c < Nsplit) ((bf16*)Cout)[(size_t)r * Nsplit + c] = __float2bfloat16(a);
                    else ((bf16*)Cout2)[(size_t)r * (N - Nsplit) + (c - Nsplit)] = __float2bfloat16(a);
                } else {
                    size_t idx = (size_t)r * N + c;
                    if constexpr (MODE == 0) {
                        ((bf16*)Cout)[idx] = __float2bfloat16(a);
                    } else if constexpr (MODE == 1) {
                        a = a / (1.f + expf(-a));
                        ((bf16*)Cout)[idx] = __float2bfloat16(a);
                    } else if constexpr (MODE == 2) {
                        a *= __bfloat162float(((const bf16*)aux)[idx]);
                        ((bf16*)Cout)[idx] = __float2bfloat16(a);
                    } else {
                        ((float*)Cout)[idx] = a + ((const float*)aux)[idx];
                    }
                }
            }
}

// ---------------------------------------------------------------- V transpose: vb[(b*2048+kv)][1024] -> vt[(b*1024+col)][2048]
__global__ void transpose_v(const bf16* __restrict__ vb, bf16* __restrict__ vt) {
    __shared__ bf16 tile[64][68];
    int kv0 = blockIdx.x * 64, c0 = blockIdx.y * 64, b = blockIdx.z;
    int t = threadIdx.x;
    int cr = t & 15, rr = t >> 4;
#pragma unroll
    for (int j = 0; j < 4; ++j) {
        int r = rr + j * 16;
        *(int2*)&tile[r][cr * 4] = *(const int2*)&vb[(size_t)(b * 2048 + kv0 + r) * 1024 + c0 + cr * 4];
    }
    __syncthreads();
#pragma unroll
    for (int j = 0; j < 4; ++j) {
        int cc = rr + j * 16;
        bf16 tmp[4];
#pragma unroll
        for (int q = 0; q < 4; ++q) tmp[q] = tile[cr * 4 + q][cc];
        *(int2*)&vt[(size_t)(b * 1024 + c0 + cc) * 2048 + kv0 + cr * 4] = *(const int2*)tmp;
    }
}

// ---------------------------------------------------------------- flash attention v2 (GQA 32q/8kv, HD=128)
__global__ __launch_bounds__(256) void attn_kernel(
    const bf16* __restrict__ Q, const bf16* __restrict__ Kb, const bf16* __restrict__ Vt,
    const float* __restrict__ mask, bf16* __restrict__ O)
{
    const int QL_ = 1024, KVL_ = 2048;
    const float scale = 0.08838834764831845f;  // 1/sqrt(128)
    int qt = blockIdx.x, h = blockIdx.y, b = blockIdx.z;
    int t = threadIdx.x, wave = t >> 6, lane = t & 63;
    int lr = lane & 15, lg = lane >> 4;
    int g = h >> 2;
    __shared__ bf16 Ksm[64 * 128];     // [kv][d], 256B rows, swizzled
    __shared__ bf16 Vsm[128 * 64];     // [d][kv], 128B rows, swizzled
    __shared__ bf16 Psm[4][16 * 72];   // per-wave P [q][kv], stride 72
    int q0 = qt * 64 + wave * 16;

    const bf16* qptr = Q + (size_t)(b * QL_ + q0 + lr) * 4096 + h * 128;
    bfv8 qf[4];
#pragma unroll
    for (int kc = 0; kc < 4; ++kc) qf[kc] = *(const bfv8*)(qptr + kc * 32 + lg * 8);

    const f32x4 zero4 = { 0.f, 0.f, 0.f, 0.f };
    f32x4 accO[8];
#pragma unroll
    for (int dt = 0; dt < 8; ++dt) accO[dt] = zero4;
    float mrow[4] = { -1e30f, -1e30f, -1e30f, -1e30f };
    float lrow[4] = { 0.f, 0.f, 0.f, 0.f };

    for (int kv0 = 0; kv0 < KVL_; kv0 += 64) {
#pragma unroll
        for (int p2 = 0; p2 < 4; ++p2) {
            int Wb = (p2 * 256 + t) * 16;
            int row = Wb >> 8;
            int col = ((Wb & 255) ^ ((row & 7) << 4)) >> 1;
            gload_lds16(Kb + (size_t)(b * KVL_ + kv0 + row) * 1024 + g * 128 + col,
                        (char*)Ksm + Wb);
        }
#pragma unroll
        for (int p2 = 0; p2 < 4; ++p2) {
            int Wb = (p2 * 256 + t) * 16;
            int row = Wb >> 7;
            int col = ((Wb & 127) ^ ((row & 7) << 4)) >> 1;
            gload_lds16(Vt + (size_t)(b * 1024 + g * 128 + row) * 2048 + kv0 + col,
                        (char*)Vsm + Wb);
        }
        __syncthreads();

        f32x4 s[4];
#pragma unroll
        for (int ct = 0; ct < 4; ++ct) {
            s[ct] = zero4;
#pragma unroll
            for (int kc = 0; kc < 4; ++kc) {
                int row = ct * 16 + lr;
                int U = row * 256 + kc * 64 + lg * 16;
                bfv8 kf = *(const bfv8*)((const char*)Ksm + (U ^ ((row & 7) << 4)));
                s[ct] = mfma16(qf[kc], kf, s[ct]);
            }
            float mv = mask[(size_t)b * KVL_ + kv0 + ct * 16 + lr];
            mv = (mv != 0.f) ? 1.f : 0.f;
#pragma unroll
            for (int i = 0; i < 4; ++i) s[ct][i] = s[ct][i] * scale + mv;
        }

        float rmx[4], mnew[4], corr[4], psum[4];
#pragma unroll
        for (int i = 0; i < 4; ++i) {
            rmx[i] = fmaxf(fmaxf(s[0][i], s[1][i]), fmaxf(s[2][i], s[3][i]));
#pragma unroll
            for (int d = 1; d < 16; d <<= 1) rmx[i] = fmaxf(rmx[i], __shfl_xor(rmx[i], d));
            mnew[i] = fmaxf(mrow[i], rmx[i]);
            corr[i] = expf(mrow[i] - mnew[i]);
            psum[i] = 0.f;
        }
#pragma unroll
        for (int ct = 0; ct < 4; ++ct)
#pragma unroll
            for (int i = 0; i < 4; ++i) {
                float pv = expf(s[ct][i] - mnew[i]);
                psum[i] += pv;
                Psm[wave][(lg * 4 + i) * 72 + ct * 16 + lr] = __float2bfloat16(pv);
            }
#pragma unroll
        for (int i = 0; i < 4; ++i) {
#pragma unroll
            for (int d = 1; d < 16; d <<= 1) psum[i] += __shfl_xor(psum[i], d);
            lrow[i] = lrow[i] * corr[i] + psum[i];
            mrow[i] = mnew[i];
        }
#pragma unroll
        for (int dt = 0; dt < 8; ++dt)
#pragma unroll
            for (int i = 0; i < 4; ++i) accO[dt][i] *= corr[i];
        __syncthreads();

        bfv8 pf0 = *(const bfv8*)&Psm[wave][lr * 72 + 0 * 32 + lg * 8];
        bfv8 pf1 = *(const bfv8*)&Psm[wave][lr * 72 + 1 * 32 + lg * 8];
#pragma unroll
        for (int dt = 0; dt < 8; ++dt) {
            int row = dt * 16 + lr;
            int U0 = row * 128 + 0 * 64 + lg * 16;
            int U1 = row * 128 + 1 * 64 + lg * 16;
            bfv8 vf0 = *(const bfv8*)((const char*)Vsm + (U0 ^ ((row & 7) << 4)));
            bfv8 vf1 = *(const bfv8*)((const char*)Vsm + (U1 ^ ((row & 7) << 4)));
            accO[dt] = mfma16(pf0, vf0, accO[dt]);
            accO[dt] = mfma16(pf1, vf1, accO[dt]);
        }
        __syncthreads();
    }

    float invl[4];
#pragma unroll
    for (int i = 0; i < 4; ++i) invl[i] = 1.f / lrow[i];
#pragma unroll
    for (int dt = 0; dt < 8; ++dt)
#pragma unroll
        for (int i = 0; i < 4; ++i)
            O[(size_t)(b * QL_ + q0 + lg * 4 + i) * 4096 + h * 128 + dt * 16 + lr] =
                __float2bfloat16(accO[dt][i] * invl[i]);
}

// ---------------------------------------------------------------- launch
extern "C" void kernel_launch(void* const* d_in, const int* in_sizes, int n_in,
                              void* d_out, int out_size, void* d_ws, size_t ws_size,
                              hipStream_t stream) {
    const float* hidden = (const float*)d_in[0];
    const float* enc    = (const float*)d_in[1];
    const float* mask   = (const float*)d_in[2];
    const float* ln1w   = (const float*)d_in[3];
    const float* ln1b   = (const float*)d_in[4];
    const float* qw     = (const float*)d_in[5];
    const float* kw     = (const float*)d_in[6];
    const float* vw     = (const float*)d_in[7];
    const float* ow     = (const float*)d_in[8];
    const float* ln2w   = (const float*)d_in[9];
    const float* ln2b   = (const float*)d_in[10];
    const float* gatew  = (const float*)d_in[11];
    const float* upw    = (const float*)d_in[12];
    const float* downw  = (const float*)d_in[13];
    float* out = (float*)d_out;

    char* ws = (char*)d_ws;
    bf16*  wbuf  = (bf16*)(ws);                       // 134,217,728 B
    bf16*  wbuf2 = (bf16*)(ws + 8388608);             // second half for kv (kw 8MB, vw 8MB)
    bf16*  h1    = (bf16*)(ws + 134217728);           // 16,777,216
    bf16*  encb  = (bf16*)(ws + 150994944);           // 33,554,432
    bf16*  qb    = (bf16*)(ws + 184549376);           // 16,777,216
    bf16*  kb    = (bf16*)(ws + 201326592);           // 8,388,608
    bf16*  vb    = (bf16*)(ws + 209715200);           // 8,388,608
    bf16*  attno = (bf16*)(ws + 218103808);           // 16,777,216
    float* h2    = (float*)(ws + 234881024);          // 33,554,432 (vt aliases pre-o-proj)
    bf16*  vt    = (bf16*)(ws + 234881024);           // 8,388,608
    bf16*  h2n   = (bf16*)(ws + 268435456);           // 16,777,216
    bf16*  g1    = (bf16*)(ws + 285212672);           // 67,108,864

    auto cvt = [&](const float* src, bf16* dst, long n) {
        cvt_kernel<<<(int)(n / 2048), 256, 0, stream>>>(src, dst, n / 8);
    };

    // encoder hidden -> bf16; LN1(hidden) -> bf16
    cvt(enc, encb, 16777216L);
    layernorm_kernel<<<2048, 256, 0, stream>>>(hidden, ln1w, ln1b, h1);

    // Q = h1 x qw^T  [2048, 4096]; rope
    cvt(qw, wbuf, 16777216L);
    gemm_p<128, 256, 0, false><<<dim3(16, 16), 512, 0, stream>>>(
        h1, wbuf, nullptr, qb, nullptr, nullptr, 2048, 4096, 4096, 0);
    rope_kernel<<<16384, 256, 0, stream>>>(qb, 32, 1024, 2048L * 32 * 64);

    // K,V fused: [4096, 2048] = encb x [kw; vw]^T, split outputs kb/vb
    cvt(kw, wbuf, 4194304L);
    cvt(vw, wbuf2, 4194304L);
    gemm_p<128, 256, 0, true><<<dim3(8, 32), 512, 0, stream>>>(
        encb, wbuf, wbuf2, kb, vb, nullptr, 4096, 2048, 4096, 1024);
    rope_kernel<<<8192, 256, 0, stream>>>(kb, 8, 2048, 4096L * 8 * 64);
    transpose_v<<<dim3(32, 16, 2), 256, 0, stream>>>(vb, vt);

    // attention
    attn_kernel<<<dim3(16, 32, 2), 256, 0, stream>>>(qb, kb, vt, mask, attno);

    // h2 = hidden + attno x ow^T (fp32)  [overwrites vt region]
    cvt(ow, wbuf, 16777216L);
    gemm_p<128, 256, 3, false><<<dim3(16, 16), 512, 0, stream>>>(
        attno, wbuf, nullptr, h2, nullptr, hidden, 2048, 4096, 4096, 0);

    // LN2 -> bf16
    layernorm_kernel<<<2048, 256, 0, stream>>>(h2, ln2w, ln2b, h2n);

    // g1 = silu(h2n x gatew^T); g1 *= h2n x upw^T
    cvt(gatew, wbuf, 67108864L);
    gemm_p<256, 256, 1, false><<<dim3(64, 8), 512, 0, stream>>>(
        h2n, wbuf, nullptr, g1, nullptr, nullptr, 2048, 16384, 4096, 0);
    cvt(upw, wbuf, 67108864L);
    gemm_p<256, 256, 2, false><<<dim3(64, 8), 512, 0, stream>>>(
        h2n, wbuf, nullptr, g1, nullptr, g1, 2048, 16384, 4096, 0);

    // out = h2 + g1 x downw^T (fp32)
    cvt(downw, wbuf, 67108864L);
    gemm_p<128, 256, 3, false><<<dim3(16, 16), 512, 0, stream>>>(
        g1, wbuf, nullptr, out, nullptr, h2, 2048, 4096, 16384, 0);
}

// Round 4
// 1573.915 us; speedup vs baseline: 1.4558x; 1.1688x over previous
//
#include <hip/hip_runtime.h>
#include <hip/hip_bf16.h>
#include <math.h>

using bf16 = __hip_bfloat16;
typedef __bf16 bfv8 __attribute__((ext_vector_type(8)));
typedef float f32x4 __attribute__((ext_vector_type(4)));

__device__ __forceinline__ f32x4 mfma16(bfv8 a, bfv8 b, f32x4 c) {
    return __builtin_amdgcn_mfma_f32_16x16x32_bf16(a, b, c, 0, 0, 0);
}

__device__ __forceinline__ void gload_lds16(const void* g, void* l) {
    __builtin_amdgcn_global_load_lds(
        (const __attribute__((address_space(1))) void*)g,
        (__attribute__((address_space(3))) void*)l, 16, 0, 0);
}

// ---------------------------------------------------------------- cvt f32->bf16
__global__ void cvt_kernel(const float* __restrict__ in, bf16* __restrict__ out, long n8) {
    long u = (long)blockIdx.x * 256 + threadIdx.x;
    if (u >= n8) return;
    const float4* p = (const float4*)in + u * 2;
    float4 a = p[0], b = p[1];
    bf16 t8[8] = { __float2bfloat16(a.x), __float2bfloat16(a.y), __float2bfloat16(a.z), __float2bfloat16(a.w),
                   __float2bfloat16(b.x), __float2bfloat16(b.y), __float2bfloat16(b.z), __float2bfloat16(b.w) };
    *(int4*)(out + u * 8) = *(const int4*)t8;
}

// ---------------------------------------------------------------- layernorm (D=4096), fp32 in -> bf16 out
__global__ void layernorm_kernel(const float* __restrict__ x, const float* __restrict__ gw,
                                 const float* __restrict__ gb, bf16* __restrict__ out)
{
    const int D = 4096;
    int row = blockIdx.x, t = threadIdx.x;
    const float4* xr = (const float4*)(x + (size_t)row * D);
    float4 v[4];
    float s1 = 0.f, s2 = 0.f;
#pragma unroll
    for (int j = 0; j < 4; ++j) {
        v[j] = xr[t + j * 256];
        s1 += v[j].x + v[j].y + v[j].z + v[j].w;
        s2 += v[j].x * v[j].x + v[j].y * v[j].y + v[j].z * v[j].z + v[j].w * v[j].w;
    }
#pragma unroll
    for (int d = 1; d < 64; d <<= 1) { s1 += __shfl_xor(s1, d); s2 += __shfl_xor(s2, d); }
    __shared__ float red[8];
    int wave = t >> 6, lane = t & 63;
    if (lane == 0) { red[wave] = s1; red[4 + wave] = s2; }
    __syncthreads();
    s1 = red[0] + red[1] + red[2] + red[3];
    s2 = red[4] + red[5] + red[6] + red[7];
    float mu = s1 * (1.f / 4096.f);
    float var = s2 * (1.f / 4096.f) - mu * mu;
    float rs = rsqrtf(var + 1e-5f);
    bf16* orow = out + (size_t)row * D;
#pragma unroll
    for (int j = 0; j < 4; ++j) {
        int base = (t + j * 256) * 4;
        float xs[4] = { v[j].x, v[j].y, v[j].z, v[j].w };
        bf16 o4[4];
#pragma unroll
        for (int c = 0; c < 4; ++c)
            o4[c] = __float2bfloat16((xs[c] - mu) * rs * gw[base + c] + gb[base + c]);
        *(int2*)(orow + base) = *(const int2*)o4;
    }
}

// ---------------------------------------------------------------- RoPE in-place on bf16 [rows, nheads*128]
__global__ void rope_kernel(bf16* __restrict__ x, int nheads, int seqlen, long total) {
    long idx = (long)blockIdx.x * 256 + threadIdx.x;
    if (idx >= total) return;
    int j = (int)(idx & 63);
    long t2 = idx >> 6;
    int h = (int)(t2 % nheads);
    long row = t2 / nheads;
    int pos = (int)(row % seqlen);
    float inv = exp2f(-(float)j * 0.20762050593046015f);  // log2(10000)/64
    float ang = (float)pos * inv;
    float s, c;
    sincosf(ang, &s, &c);
    bf16* p = x + row * ((long)nheads * 128) + (long)h * 128 + j;
    float x0 = __bfloat162float(p[0]);
    float x1 = __bfloat162float(p[64]);
    p[0]  = __float2bfloat16(x0 * c - x1 * s);
    p[64] = __float2bfloat16(x1 * c + x0 * s);
}

// ---------------------------------------------------------------- pipelined GEMM, BK=32, 3-buf LDS
// C[M,N] = A[M,K] x W[N,K]^T. 512 thr = 8 waves (2M x 4N); per-wave (BM/2) x (BN/4).
// LDS pair-swizzle: phys = U ^ (((U>>7)&7)<<4) (conflict-free, verified 0 SQ_LDS_BANK_CONFLICT r3).
// Pipeline ledger (verified r3): compute buf[t%3]; stage t+2 -> buf[(t+2)%3];
// trailing s_waitcnt vmcnt(SLD) leaves tile t+2's loads in flight across the barrier.
// XCD 2D-chunk mapping: block bid -> XCD bid%8 (HW round-robin); each XCD owns a
// CM x CN tile chunk (square-ish minimizes per-XCD A+W panel fetch through its
// private 4MB L2). XCD chunk grid is (8/XN) x XN; slot walks row-major in chunk.
// MODE 0: bf16; 1: silu->bf16; 2: *aux(bf16)->bf16; 3: +aux(f32)->f32
template<int BM, int BN, int MODE, bool DUAL, int CM, int CN, int XN>
__global__ __launch_bounds__(512, 2) void gemm_p(
        const bf16* __restrict__ A, const bf16* __restrict__ W, const bf16* __restrict__ W2,
        void* __restrict__ Cout, void* __restrict__ Cout2, const void* __restrict__ aux,
        int M, int N, int K, int Nsplit)
{
    constexpr int MF = BM / 32;           // m-frags per wave
    constexpr int NF = BN / 64;           // n-frags per wave
    constexpr int ALD = BM / 128;         // A stage loads per thread
    constexpr int BLD = BN / 128;         // B stage loads per thread
    constexpr int SLD = ALD + BLD;
    __shared__ bf16 lds[3][(BM + BN) * 32];

    const int t = threadIdx.x;
    const int wid = t >> 6, lane = t & 63;
    const int lr = lane & 15, lg = lane >> 4;
    const int wr = wid >> 2, wc = wid & 3;
    // 2D-chunked XCD mapping
    const int bid = blockIdx.x;
    const int xcd = bid & 7, slot = bid >> 3;
    const int sm = slot / CN, sn = slot % CN;
    const int xm = xcd / XN, xn = xcd % XN;
    const int bm = (xm * CM + sm) * BM;
    const int bn = (xn * CN + sn) * BN;

    auto stage = [&](int tt, int buf) {
        const int k0 = tt * 32;
        char* ldsA = (char*)&lds[buf][0];
#pragma unroll
        for (int c = 0; c < ALD; ++c) {
            int Wb = (t + c * 512) * 16;
            int L = Wb ^ (((Wb >> 7) & 7) << 4);
            int row = L >> 6, colb = L & 63;
            gload_lds16(A + (size_t)(bm + row) * K + k0 + (colb >> 1), ldsA + Wb);
        }
        char* ldsB = (char*)&lds[buf][BM * 32];
#pragma unroll
        for (int c = 0; c < BLD; ++c) {
            int Wb = (t + c * 512) * 16;
            int L = Wb ^ (((Wb >> 7) & 7) << 4);
            int row = L >> 6, colb = L & 63;
            const bf16* src;
            if constexpr (DUAL) {
                int nr = bn + row;
                src = (nr >= Nsplit) ? W2 + (size_t)(nr - Nsplit) * K + k0 + (colb >> 1)
                                     : W  + (size_t)nr * K + k0 + (colb >> 1);
            } else {
                src = W + (size_t)(bn + row) * K + k0 + (colb >> 1);
            }
            gload_lds16(src, ldsB + Wb);
        }
    };

    const f32x4 zero4 = { 0.f, 0.f, 0.f, 0.f };
    f32x4 acc[MF][NF];
#pragma unroll
    for (int m = 0; m < MF; ++m)
#pragma unroll
        for (int n = 0; n < NF; ++n) acc[m][n] = zero4;

    const int T = K >> 5;
    stage(0, 0);
    stage(1, 1);
    if constexpr (SLD == 4) asm volatile("s_waitcnt vmcnt(4)" ::: "memory");
    else                    asm volatile("s_waitcnt vmcnt(3)" ::: "memory");
    __builtin_amdgcn_s_barrier();
    __builtin_amdgcn_sched_barrier(0);

    for (int tt = 0; tt < T; ++tt) {
        const int buf = tt % 3;
        bfv8 af[MF], bfr[NF];
#pragma unroll
        for (int m = 0; m < MF; ++m) {
            int row = wr * (BM / 2) + m * 16 + lr;
            int U = row * 64 + lg * 16;
            af[m] = *(const bfv8*)((const char*)&lds[buf][0] + (U ^ (((U >> 7) & 7) << 4)));
        }
#pragma unroll
        for (int n = 0; n < NF; ++n) {
            int row = wc * (BN / 4) + n * 16 + lr;
            int U = row * 64 + lg * 16;
            bfr[n] = *(const bfv8*)((const char*)&lds[buf][BM * 32] + (U ^ (((U >> 7) & 7) << 4)));
        }
        if (tt + 2 < T) stage(tt + 2, (tt + 2) % 3);
        __builtin_amdgcn_s_setprio(1);
#pragma unroll
        for (int m = 0; m < MF; ++m)
#pragma unroll
            for (int n = 0; n < NF; ++n)
                acc[m][n] = mfma16(af[m], bfr[n], acc[m][n]);
        __builtin_amdgcn_s_setprio(0);
        if (tt + 2 < T) {
            if constexpr (SLD == 4) asm volatile("s_waitcnt vmcnt(4)" ::: "memory");
            else                    asm volatile("s_waitcnt vmcnt(3)" ::: "memory");
        } else {
            asm volatile("s_waitcnt vmcnt(0)" ::: "memory");
        }
        __builtin_amdgcn_s_barrier();
        __builtin_amdgcn_sched_barrier(0);
    }

    const int r0 = bm + wr * (BM / 2), c0 = bn + wc * (BN / 4);
#pragma unroll
    for (int m = 0; m < MF; ++m)
#pragma unroll
        for (int n = 0; n < NF; ++n)
#pragma unroll
            for (int i = 0; i < 4; ++i) {
                int r = r0 + m * 16 + lg * 4 + i;
                int c = c0 + n * 16 + lr;
                float a = acc[m][n][i];
                if constexpr (DUAL) {
                    if (c < Nsplit) ((bf16*)Cout)[(size_t)r * Nsplit + c] = __float2bfloat16(a);
                    else ((bf16*)Cout2)[(size_t)r * (N - Nsplit) + (c - Nsplit)] = __float2bfloat16(a);
                } else {
                    size_t idx = (size_t)r * N + c;
                    if constexpr (MODE == 0) {
                        ((bf16*)Cout)[idx] = __float2bfloat16(a);
                    } else if constexpr (MODE == 1) {
                        a = a / (1.f + expf(-a));
                        ((bf16*)Cout)[idx] = __float2bfloat16(a);
                    } else if constexpr (MODE == 2) {
                        a *= __bfloat162float(((const bf16*)aux)[idx]);
                        ((bf16*)Cout)[idx] = __float2bfloat16(a);
                    } else {
                        ((float*)Cout)[idx] = a + ((const float*)aux)[idx];
                    }
                }
            }
}

// ---------------------------------------------------------------- V transpose: vb[(b*2048+kv)][1024] -> vt[(b*1024+col)][2048]
__global__ void transpose_v(const bf16* __restrict__ vb, bf16* __restrict__ vt) {
    __shared__ bf16 tile[64][68];
    int kv0 = blockIdx.x * 64, c0 = blockIdx.y * 64, b = blockIdx.z;
    int t = threadIdx.x;
    int cr = t & 15, rr = t >> 4;
#pragma unroll
    for (int j = 0; j < 4; ++j) {
        int r = rr + j * 16;
        *(int2*)&tile[r][cr * 4] = *(const int2*)&vb[(size_t)(b * 2048 + kv0 + r) * 1024 + c0 + cr * 4];
    }
    __syncthreads();
#pragma unroll
    for (int j = 0; j < 4; ++j) {
        int cc = rr + j * 16;
        bf16 tmp[4];
#pragma unroll
        for (int q = 0; q < 4; ++q) tmp[q] = tile[cr * 4 + q][cc];
        *(int2*)&vt[(size_t)(b * 1024 + c0 + cc) * 2048 + kv0 + cr * 4] = *(const int2*)tmp;
    }
}

// ---------------------------------------------------------------- flash attention v2 (GQA 32q/8kv, HD=128)
__global__ __launch_bounds__(256) void attn_kernel(
    const bf16* __restrict__ Q, const bf16* __restrict__ Kb, const bf16* __restrict__ Vt,
    const float* __restrict__ mask, bf16* __restrict__ O)
{
    const int QL_ = 1024, KVL_ = 2048;
    const float scale = 0.08838834764831845f;  // 1/sqrt(128)
    int qt = blockIdx.x, h = blockIdx.y, b = blockIdx.z;
    int t = threadIdx.x, wave = t >> 6, lane = t & 63;
    int lr = lane & 15, lg = lane >> 4;
    int g = h >> 2;
    __shared__ bf16 Ksm[64 * 128];     // [kv][d], 256B rows, swizzled
    __shared__ bf16 Vsm[128 * 64];     // [d][kv], 128B rows, swizzled
    __shared__ bf16 Psm[4][16 * 72];   // per-wave P [q][kv], stride 72
    int q0 = qt * 64 + wave * 16;

    const bf16* qptr = Q + (size_t)(b * QL_ + q0 + lr) * 4096 + h * 128;
    bfv8 qf[4];
#pragma unroll
    for (int kc = 0; kc < 4; ++kc) qf[kc] = *(const bfv8*)(qptr + kc * 32 + lg * 8);

    const f32x4 zero4 = { 0.f, 0.f, 0.f, 0.f };
    f32x4 accO[8];
#pragma unroll
    for (int dt = 0; dt < 8; ++dt) accO[dt] = zero4;
    float mrow[4] = { -1e30f, -1e30f, -1e30f, -1e30f };
    float lrow[4] = { 0.f, 0.f, 0.f, 0.f };

    for (int kv0 = 0; kv0 < KVL_; kv0 += 64) {
#pragma unroll
        for (int p2 = 0; p2 < 4; ++p2) {
            int Wb = (p2 * 256 + t) * 16;
            int row = Wb >> 8;
            int col = ((Wb & 255) ^ ((row & 7) << 4)) >> 1;
            gload_lds16(Kb + (size_t)(b * KVL_ + kv0 + row) * 1024 + g * 128 + col,
                        (char*)Ksm + Wb);
        }
#pragma unroll
        for (int p2 = 0; p2 < 4; ++p2) {
            int Wb = (p2 * 256 + t) * 16;
            int row = Wb >> 7;
            int col = ((Wb & 127) ^ ((row & 7) << 4)) >> 1;
            gload_lds16(Vt + (size_t)(b * 1024 + g * 128 + row) * 2048 + kv0 + col,
                        (char*)Vsm + Wb);
        }
        __syncthreads();

        f32x4 s[4];
#pragma unroll
        for (int ct = 0; ct < 4; ++ct) {
            s[ct] = zero4;
#pragma unroll
            for (int kc = 0; kc < 4; ++kc) {
                int row = ct * 16 + lr;
                int U = row * 256 + kc * 64 + lg * 16;
                bfv8 kf = *(const bfv8*)((const char*)Ksm + (U ^ ((row & 7) << 4)));
                s[ct] = mfma16(qf[kc], kf, s[ct]);
            }
            float mv = mask[(size_t)b * KVL_ + kv0 + ct * 16 + lr];
            mv = (mv != 0.f) ? 1.f : 0.f;
#pragma unroll
            for (int i = 0; i < 4; ++i) s[ct][i] = s[ct][i] * scale + mv;
        }

        float rmx[4], mnew[4], corr[4], psum[4];
#pragma unroll
        for (int i = 0; i < 4; ++i) {
            rmx[i] = fmaxf(fmaxf(s[0][i], s[1][i]), fmaxf(s[2][i], s[3][i]));
#pragma unroll
            for (int d = 1; d < 16; d <<= 1) rmx[i] = fmaxf(rmx[i], __shfl_xor(rmx[i], d));
            mnew[i] = fmaxf(mrow[i], rmx[i]);
            corr[i] = expf(mrow[i] - mnew[i]);
            psum[i] = 0.f;
        }
#pragma unroll
        for (int ct = 0; ct < 4; ++ct)
#pragma unroll
            for (int i = 0; i < 4; ++i) {
                float pv = expf(s[ct][i] - mnew[i]);
                psum[i] += pv;
                Psm[wave][(lg * 4 + i) * 72 + ct * 16 + lr] = __float2bfloat16(pv);
            }
#pragma unroll
        for (int i = 0; i < 4; ++i) {
#pragma unroll
            for (int d = 1; d < 16; d <<= 1) psum[i] += __shfl_xor(psum[i], d);
            lrow[i] = lrow[i] * corr[i] + psum[i];
            mrow[i] = mnew[i];
        }
#pragma unroll
        for (int dt = 0; dt < 8; ++dt)
#pragma unroll
            for (int i = 0; i < 4; ++i) accO[dt][i] *= corr[i];
        __syncthreads();

        bfv8 pf0 = *(const bfv8*)&Psm[wave][lr * 72 + 0 * 32 + lg * 8];
        bfv8 pf1 = *(const bfv8*)&Psm[wave][lr * 72 + 1 * 32 + lg * 8];
#pragma unroll
        for (int dt = 0; dt < 8; ++dt) {
            int row = dt * 16 + lr;
            int U0 = row * 128 + 0 * 64 + lg * 16;
            int U1 = row * 128 + 1 * 64 + lg * 16;
            bfv8 vf0 = *(const bfv8*)((const char*)Vsm + (U0 ^ ((row & 7) << 4)));
            bfv8 vf1 = *(const bfv8*)((const char*)Vsm + (U1 ^ ((row & 7) << 4)));
            accO[dt] = mfma16(pf0, vf0, accO[dt]);
            accO[dt] = mfma16(pf1, vf1, accO[dt]);
        }
        __syncthreads();
    }

    float invl[4];
#pragma unroll
    for (int i = 0; i < 4; ++i) invl[i] = 1.f / lrow[i];
#pragma unroll
    for (int dt = 0; dt < 8; ++dt)
#pragma unroll
        for (int i = 0; i < 4; ++i)
            O[(size_t)(b * QL_ + q0 + lg * 4 + i) * 4096 + h * 128 + dt * 16 + lr] =
                __float2bfloat16(accO[dt][i] * invl[i]);
}

// ---------------------------------------------------------------- launch
extern "C" void kernel_launch(void* const* d_in, const int* in_sizes, int n_in,
                              void* d_out, int out_size, void* d_ws, size_t ws_size,
                              hipStream_t stream) {
    const float* hidden = (const float*)d_in[0];
    const float* enc    = (const float*)d_in[1];
    const float* mask   = (const float*)d_in[2];
    const float* ln1w   = (const float*)d_in[3];
    const float* ln1b   = (const float*)d_in[4];
    const float* qw     = (const float*)d_in[5];
    const float* kw     = (const float*)d_in[6];
    const float* vw     = (const float*)d_in[7];
    const float* ow     = (const float*)d_in[8];
    const float* ln2w   = (const float*)d_in[9];
    const float* ln2b   = (const float*)d_in[10];
    const float* gatew  = (const float*)d_in[11];
    const float* upw    = (const float*)d_in[12];
    const float* downw  = (const float*)d_in[13];
    float* out = (float*)d_out;

    char* ws = (char*)d_ws;
    bf16*  wbuf  = (bf16*)(ws);                       // 134,217,728 B
    bf16*  wbuf2 = (bf16*)(ws + 8388608);             // second half for kv (kw 8MB, vw 8MB)
    bf16*  h1    = (bf16*)(ws + 134217728);           // 16,777,216
    bf16*  encb  = (bf16*)(ws + 150994944);           // 33,554,432
    bf16*  qb    = (bf16*)(ws + 184549376);           // 16,777,216
    bf16*  kb    = (bf16*)(ws + 201326592);           // 8,388,608
    bf16*  vb    = (bf16*)(ws + 209715200);           // 8,388,608
    bf16*  attno = (bf16*)(ws + 218103808);           // 16,777,216
    float* h2    = (float*)(ws + 234881024);          // 33,554,432 (vt aliases pre-o-proj)
    bf16*  vt    = (bf16*)(ws + 234881024);           // 8,388,608
    bf16*  h2n   = (bf16*)(ws + 268435456);           // 16,777,216
    bf16*  g1    = (bf16*)(ws + 285212672);           // 67,108,864

    auto cvt = [&](const float* src, bf16* dst, long n) {
        cvt_kernel<<<(int)(n / 2048), 256, 0, stream>>>(src, dst, n / 8);
    };

    // encoder hidden -> bf16; LN1(hidden) -> bf16
    cvt(enc, encb, 16777216L);
    layernorm_kernel<<<2048, 256, 0, stream>>>(hidden, ln1w, ln1b, h1);

    // Q = h1 x qw^T  [2048, 4096]; tiles 16m x 16n, XCD chunk 8x4 (XCD grid 2x4)
    cvt(qw, wbuf, 16777216L);
    gemm_p<128, 256, 0, false, 8, 4, 4><<<256, 512, 0, stream>>>(
        h1, wbuf, nullptr, qb, nullptr, nullptr, 2048, 4096, 4096, 0);
    rope_kernel<<<16384, 256, 0, stream>>>(qb, 32, 1024, 2048L * 32 * 64);

    // K,V fused: [4096, 2048]; tiles 32m x 8n, XCD chunk 8x4 (XCD grid 4x2)
    cvt(kw, wbuf, 4194304L);
    cvt(vw, wbuf2, 4194304L);
    gemm_p<128, 256, 0, true, 8, 4, 2><<<256, 512, 0, stream>>>(
        encb, wbuf, wbuf2, kb, vb, nullptr, 4096, 2048, 4096, 1024);
    rope_kernel<<<8192, 256, 0, stream>>>(kb, 8, 2048, 4096L * 8 * 64);
    transpose_v<<<dim3(32, 16, 2), 256, 0, stream>>>(vb, vt);

    // attention
    attn_kernel<<<dim3(16, 32, 2), 256, 0, stream>>>(qb, kb, vt, mask, attno);

    // h2 = hidden + attno x ow^T (fp32); tiles 16x16, chunk 8x4
    cvt(ow, wbuf, 16777216L);
    gemm_p<128, 256, 3, false, 8, 4, 4><<<256, 512, 0, stream>>>(
        attno, wbuf, nullptr, h2, nullptr, hidden, 2048, 4096, 4096, 0);

    // LN2 -> bf16
    layernorm_kernel<<<2048, 256, 0, stream>>>(h2, ln2w, ln2b, h2n);

    // g1 = silu(h2n x gatew^T); g1 *= h2n x upw^T; tiles 8m x 64n, chunk 8x8 (XCD grid 1x8)
    cvt(gatew, wbuf, 67108864L);
    gemm_p<256, 256, 1, false, 8, 8, 8><<<512, 512, 0, stream>>>(
        h2n, wbuf, nullptr, g1, nullptr, nullptr, 2048, 16384, 4096, 0);
    cvt(upw, wbuf, 67108864L);
    gemm_p<256, 256, 2, false, 8, 8, 8><<<512, 512, 0, stream>>>(
        h2n, wbuf, nullptr, g1, nullptr, g1, 2048, 16384, 4096, 0);

    // out = h2 + g1 x downw^T (fp32); tiles 16m x 16n, chunk 8x4
    cvt(downw, wbuf, 67108864L);
    gemm_p<128, 256, 3, false, 8, 4, 4><<<256, 512, 0, stream>>>(
        g1, wbuf, nullptr, out, nullptr, h2, 2048, 4096, 16384, 0);
}